// Round 15
// baseline (314.087 us; speedup 1.0000x reference)
//
#include <hip/hip_runtime.h>

#define AP 40      // padded LDS K-stride (bf16): 80B rows -> 2-way bank aliasing (free)
#define H2P 136    // h2 LDS row stride (bf16): 272B -> 2-way
#define PB 120     // hist/bucket-sort pass blocks
#define NPB 256    // nodes per bucket (d >> 8)
#define NBUKMAX 512
#define CAPE 8192  // LDS stage capacity (edges per bucket)

typedef short bf16x8 __attribute__((ext_vector_type(8)));
typedef float f32x4 __attribute__((ext_vector_type(4)));

static __device__ __forceinline__ ushort f2bf(float f) {
  unsigned u = __float_as_uint(f);
  unsigned r = (u + 0x7fffu + ((u >> 16) & 1u)) >> 16;  // RNE
  return (ushort)r;
}
static __device__ __forceinline__ float bflo(unsigned u) { return __uint_as_float(u << 16); }
static __device__ __forceinline__ float bfhi(unsigned u) { return __uint_as_float(u & 0xffff0000u); }
static __device__ __forceinline__ unsigned packbf(float lo, float hi) {
  return (unsigned)f2bf(lo) | ((unsigned)f2bf(hi) << 16);
}

// ---- merged: src-degree byte-plane histogram + dst bucket histogram (one edge read) ----
__global__ __launch_bounds__(256) void k_hist2(const int* __restrict__ src,
                                               const int* __restrict__ dst, int E,
                                               unsigned* __restrict__ planes, int HW,
                                               int* __restrict__ hist) {
  __shared__ unsigned lds[25600];  // 100KB byte counters (up to 102400 nodes)
  __shared__ int cnt[NBUKMAX];
  const int per = (E + PB - 1) / PB;
  const int s0 = blockIdx.x * per;
  const int s1 = min(E, s0 + per);
  for (int i = threadIdx.x; i < HW; i += 256) lds[i] = 0u;
  for (int i = threadIdx.x; i < NBUKMAX; i += 256) cnt[i] = 0;
  __syncthreads();
  for (int j = s0 + threadIdx.x; j < s1; j += 256) {
    int k = src[j];
    atomicAdd(&lds[k >> 2], 1u << ((k & 3) * 8));
    atomicAdd(&cnt[dst[j] >> 8], 1);
  }
  __syncthreads();
  unsigned* out = planes + (size_t)blockIdx.x * HW;
  for (int i = threadIdx.x; i < HW; i += 256) out[i] = lds[i];
  for (int i = threadIdx.x; i < NBUKMAX; i += 256) hist[i * PB + blockIdx.x] = cnt[i];
}

// ---- merged: plane-reduce -> nrm | weight cvt (w1 in fragment order) | bucket scan ----
__global__ void k_reduce_cvt(const unsigned* __restrict__ planes, int HW,
                             float* __restrict__ nrm, int N, int nrb,
                             const float* __restrict__ w1, const float* __restrict__ w2,
                             const float* __restrict__ w3, ushort* __restrict__ w1P,
                             ushort* __restrict__ w2T, ushort* __restrict__ w3b,
                             int* __restrict__ hist) {
  __shared__ int s[256];
  if ((int)blockIdx.x < nrb) {
    int w = blockIdx.x * 256 + threadIdx.x;
    if (w >= HW) return;
    const unsigned* base = planes + w;
    unsigned c0 = 0, c1 = 0, c2 = 0, c3 = 0;
    for (int b = 0; b < PB; b++) {
      unsigned u = base[(size_t)b * HW];
      c0 += u & 255u; c1 += (u >> 8) & 255u; c2 += (u >> 16) & 255u; c3 += u >> 24;
    }
    int n0 = w * 4;
    unsigned c[4] = {c0, c1, c2, c3};
#pragma unroll
    for (int j = 0; j < 4; j++)
      if (n0 + j < N) {
        float d = (float)c[j];
        if (d < 1.f) d = 1.f;
        nrm[n0 + j] = 1.f / sqrtf(d);
      }
  } else if ((int)blockIdx.x < nrb + 200) {
    int i = (blockIdx.x - nrb) * 256 + threadIdx.x;
    if (i < 32768) {
      // w1P: MFMA-A-fragment order. frag=(k0s*8+ni), elem=(lane,e)
      int frag = i >> 9, within = i & 511;
      int lane = within >> 3, e = within & 7;
      int k0s = frag >> 3, ni = frag & 7;
      int row = ni * 16 + (lane & 15);
      int col = k0s * 32 + (lane >> 4) * 8 + e;
      w1P[i] = f2bf(w1[col * 128 + row]);
    } else if (i < 49152) {     // w2T [128 c][128 k] <- w2 [128][128]
      int j = i - 32768;
      int c = j >> 7, k = j & 127;
      w2T[j] = f2bf(w2[k * 128 + c]);
    } else if (i < 51200) {     // w3b flat [16][128]
      int j = i - 49152;
      w3b[j] = f2bf(w3[j]);
    }
  } else {
    // exclusive scan of bucket totals; rewrite hist rows as running base offsets
    int t = threadIdx.x;
    int b0 = t * 2, b1 = t * 2 + 1;
    int tot0 = 0, tot1 = 0;
    for (int blk = 0; blk < PB; blk++) tot0 += hist[b0 * PB + blk];
    for (int blk = 0; blk < PB; blk++) tot1 += hist[b1 * PB + blk];
    int pair = tot0 + tot1;
    s[t] = pair;
    __syncthreads();
    for (int o = 1; o < 256; o <<= 1) {
      int x = (t >= o) ? s[t - o] : 0;
      __syncthreads();
      s[t] += x;
      __syncthreads();
    }
    int base = s[t] - pair;
    for (int blk = 0; blk < PB; blk++) { int v = hist[b0 * PB + blk]; hist[b0 * PB + blk] = base; base += v; }
    for (int blk = 0; blk < PB; blk++) { int v = hist[b1 * PB + blk]; hist[b1 * PB + blk] = base; base += v; }
  }
}

// ---- p1: bucket-scatter (standalone for clean attribution) ----
__global__ __launch_bounds__(256) void k_p1_scatter(const int* __restrict__ src,
                                                    const int* __restrict__ dst, int E,
                                                    const int* __restrict__ hist,
                                                    unsigned* __restrict__ pairs) {
  __shared__ int cur[NBUKMAX];
  for (int i = threadIdx.x; i < NBUKMAX; i += 256) cur[i] = hist[i * PB + blockIdx.x];
  __syncthreads();
  const int per = (E + PB - 1) / PB;
  const int s0 = blockIdx.x * per;
  const int s1 = min(E, s0 + per);
  for (int j = s0 + threadIdx.x; j < s1; j += 256) {
    int d = dst[j];
    int pos = atomicAdd(&cur[d >> 8], 1);
    pairs[pos] = ((unsigned)src[j] << 8) | (unsigned)(d & 255);
  }
}

// ---- GEMM1 direct-fragment, 128 rows/block (2 row-groups/wave): no LDS, no barriers ----
// Xb[r,:] = bf16(nrm[r]*(feat[r,:] @ w1)); lane loads its MFMA B-fragment straight from
// feat, converts fp32->bf16 in-register; w1 A-fragments from w1P (coalesced, L2-resident).
__global__ __launch_bounds__(256) void k_gemm1(const float* __restrict__ feat,
                                               const ushort* __restrict__ w1P,
                                               const float* __restrict__ nrm,
                                               ushort* __restrict__ Xb, int N) {
  const int tid = threadIdx.x;
  const int row0 = blockIdx.x * 128;
  const int wv = tid >> 6, lane = tid & 63;
  const int rbase = wv * 32;
  const int lr = lane & 15;
  const int kh = (lane >> 4) * 8;  // k-offset within each 32-wide chunk

  const int gr0 = row0 + rbase + lr;        // row-group 0
  const int gr1 = gr0 + 16;                 // row-group 1
  const bool v0 = (gr0 < N), v1 = (gr1 < N);
  const float* fb0 = feat + (size_t)gr0 * 256 + kh;
  const float* fb1 = feat + (size_t)gr1 * 256 + kh;

  f32x4 acc[2][8];
#pragma unroll
  for (int mi = 0; mi < 2; mi++)
#pragma unroll
    for (int ni = 0; ni < 8; ni++) acc[mi][ni] = (f32x4)0.f;

#pragma unroll
  for (int ks = 0; ks < 8; ks++) {
    float4 a0 = make_float4(0.f, 0.f, 0.f, 0.f), b0 = a0, a1 = a0, b1 = a0;
    if (v0) { a0 = *(const float4*)(fb0 + ks * 32); b0 = *(const float4*)(fb0 + ks * 32 + 4); }
    if (v1) { a1 = *(const float4*)(fb1 + ks * 32); b1 = *(const float4*)(fb1 + ks * 32 + 4); }
    union { bf16x8 v; ushort u[8]; } f0, f1;
    f0.u[0] = f2bf(a0.x); f0.u[1] = f2bf(a0.y); f0.u[2] = f2bf(a0.z); f0.u[3] = f2bf(a0.w);
    f0.u[4] = f2bf(b0.x); f0.u[5] = f2bf(b0.y); f0.u[6] = f2bf(b0.z); f0.u[7] = f2bf(b0.w);
    f1.u[0] = f2bf(a1.x); f1.u[1] = f2bf(a1.y); f1.u[2] = f2bf(a1.z); f1.u[3] = f2bf(a1.w);
    f1.u[4] = f2bf(b1.x); f1.u[5] = f2bf(b1.y); f1.u[6] = f2bf(b1.z); f1.u[7] = f2bf(b1.w);
    const ushort* wbase = w1P + (size_t)ks * 8 * 512 + lane * 8;
#pragma unroll
    for (int ni = 0; ni < 8; ni++) {  // coalesced 1KB wave-reads from L2
      bf16x8 afrag = *(const bf16x8*)&wbase[ni * 512];
      acc[0][ni] = __builtin_amdgcn_mfma_f32_16x16x32_bf16(afrag, f0.v, acc[0][ni], 0, 0, 0);
      acc[1][ni] = __builtin_amdgcn_mfma_f32_16x16x32_bf16(afrag, f1.v, acc[1][ni], 0, 0, 0);
    }
  }
#pragma unroll
  for (int mi = 0; mi < 2; mi++) {
    int gr = (mi ? gr1 : gr0);
    if (gr < N) {
      float nv = nrm[gr];
#pragma unroll
      for (int ni = 0; ni < 8; ni++) {
        int c0 = ni * 16 + (lane >> 4) * 4;
        ushort4 u;
        u.x = f2bf(acc[mi][ni][0] * nv);
        u.y = f2bf(acc[mi][ni][1] * nv);
        u.z = f2bf(acc[mi][ni][2] * nv);
        u.w = f2bf(acc[mi][ni][3] * nv);
        *(ushort4*)&Xb[(size_t)gr * 128 + c0] = u;
      }
    }
  }
}

// ---- p2: per-bucket CSR segment (count -> scan -> row_start + coalesced placement) ----
__global__ __launch_bounds__(256) void k_p2_place(const unsigned* __restrict__ pairs,
                                                  const int* __restrict__ hist,
                                                  int* __restrict__ csr,
                                                  int* __restrict__ row_start,
                                                  int N, int E) {
  __shared__ int stage[CAPE];
  __shared__ int cnt[NPB];
  __shared__ int scn[NPB];
  const int b = blockIdx.x;
  const int t = threadIdx.x;
  const int n0 = b << 8;
  const int n1 = min(N, n0 + NPB);
  const int nn = n1 - n0;
  const int e0 = hist[b * PB];
  const int e1 = hist[(b + 1) * PB];
  for (int i = t; i < nn; i += 256) cnt[i] = 0;
  __syncthreads();
  for (int j = e0 + t; j < e1; j += 256) atomicAdd(&cnt[pairs[j] & 255u], 1);
  __syncthreads();
  int v = (t < nn) ? cnt[t] : 0;
  scn[t] = v;
  __syncthreads();
  for (int o = 1; o < NPB; o <<= 1) {
    int x = (t >= o) ? scn[t - o] : 0;
    __syncthreads();
    scn[t] += x;
    __syncthreads();
  }
  int excl = scn[t] - v;
  if (t < nn) row_start[n0 + t] = e0 + excl;
  if (t == NPB - 1 && n1 == N) row_start[N] = e0 + scn[t];
  __syncthreads();
  if (t < nn) cnt[t] = excl;
  __syncthreads();
  const int seg = e1 - e0;
  if (seg <= CAPE) {
    for (int j = e0 + t; j < e1; j += 256) {
      unsigned pr = pairs[j];
      int rpos = atomicAdd(&cnt[pr & 255u], 1);
      stage[rpos] = (int)(pr >> 8);
    }
    __syncthreads();
    for (int j = t; j < seg; j += 256) csr[e0 + j] = stage[j];
  } else {
    for (int j = e0 + t; j < e1; j += 256) {
      unsigned pr = pairs[j];
      int rpos = atomicAdd(&cnt[pr & 255u], 1);
      csr[e0 + rpos] = (int)(pr >> 8);
    }
  }
}

// ---------------- Edge aggregation (bf16 in, fp32 accum, bf16 out) ----------------
// fused=1: Out = bf16(relu(sum*nrm+bias)*nrm) ; fused=0: Out = bf16(sum)
__global__ __launch_bounds__(256) void k_agg_bf(const ushort* __restrict__ Xin,
                                                const int* __restrict__ rs,
                                                const int* __restrict__ csr,
                                                const float* __restrict__ nrm,
                                                const float* __restrict__ bias,
                                                ushort* __restrict__ Out, int N, int fused) {
  const int wv = threadIdx.x >> 6, lane = threadIdx.x & 63;
  const int d = blockIdx.x * 4 + wv;
  if (d >= N) return;
  const unsigned* X = (const unsigned*)Xin;
  int s0 = rs[d], s1 = rs[d + 1];
  float a0 = 0.f, a1 = 0.f;
  int j = s0;
  for (; j + 4 <= s1; j += 4) {
    int i0 = csr[j], i1 = csr[j + 1], i2 = csr[j + 2], i3 = csr[j + 3];
    unsigned u0 = X[(size_t)i0 * 64 + lane];
    unsigned u1 = X[(size_t)i1 * 64 + lane];
    unsigned u2 = X[(size_t)i2 * 64 + lane];
    unsigned u3 = X[(size_t)i3 * 64 + lane];
    a0 += (bflo(u0) + bflo(u1)) + (bflo(u2) + bflo(u3));
    a1 += (bfhi(u0) + bfhi(u1)) + (bfhi(u2) + bfhi(u3));
  }
  for (; j < s1; j++) {
    unsigned u = X[(size_t)csr[j] * 64 + lane];
    a0 += bflo(u);
    a1 += bfhi(u);
  }
  unsigned o;
  if (fused) {
    float nv = nrm[d];
    float2 b = *(const float2*)&bias[lane * 2];
    float h0 = fmaxf(a0 * nv + b.x, 0.f) * nv;
    float h1 = fmaxf(a1 * nv + b.y, 0.f) * nv;
    o = packbf(h0, h1);
  } else {
    o = packbf(a0, a1);
  }
  ((unsigned*)Out)[(size_t)d * 64 + lane] = o;
}

// ---------------- GEMM2+3 (MFMA): h2=relu((Agg2@w2)*nrm+b2); out=h2@w3^T+b3 (x2) ----------------
__global__ __launch_bounds__(256) void k_gemm23_mfma(const ushort* __restrict__ Agg2,
                                                     const float* __restrict__ nrm,
                                                     const ushort* __restrict__ w2T,
                                                     const float* __restrict__ b2,
                                                     const ushort* __restrict__ w3b,
                                                     const float* __restrict__ b3,
                                                     float* __restrict__ out, int N) {
  __shared__ __align__(16) char lds_raw[128 * H2P * 2];
  ushort* As = (ushort*)lds_raw;
  ushort* Bs = As + 128 * AP;
  ushort* h2s = (ushort*)lds_raw;

  const int tid = threadIdx.x;
  const int row0 = blockIdx.x * 128;
  const int wv = tid >> 6, lane = tid & 63;
  const int rbase = wv * 32;
  const int lr = lane & 15;
  const int kl = (lane >> 4) * 8;

  f32x4 acc[8][2];
#pragma unroll
  for (int ni = 0; ni < 8; ni++)
#pragma unroll
    for (int mi = 0; mi < 2; mi++) acc[ni][mi] = (f32x4)0.f;

  for (int k0 = 0; k0 < 128; k0 += 32) {
    __syncthreads();
#pragma unroll
    for (int j = 0; j < 4; j++) {
      int e = (tid + j * 256) * 4;
      int r = e >> 5, k = e & 31;
      int gr = row0 + r;
      ushort4 v = make_ushort4(0, 0, 0, 0);
      if (gr < N) v = *(const ushort4*)&Agg2[(size_t)gr * 128 + k0 + k];
      *(ushort4*)&As[r * AP + k] = v;
    }
#pragma unroll
    for (int j = 0; j < 4; j++) {
      int e = (tid + j * 256) * 4;
      int c = e >> 5, k = e & 31;
      ushort4 v = *(const ushort4*)&w2T[(size_t)c * 128 + k0 + k];
      *(ushort4*)&Bs[c * AP + k] = v;
    }
    __syncthreads();
    bf16x8 bfrag[2], afrag[8];
#pragma unroll
    for (int mi = 0; mi < 2; mi++)
      bfrag[mi] = *(const bf16x8*)&As[(rbase + mi * 16 + lr) * AP + kl];
#pragma unroll
    for (int ni = 0; ni < 8; ni++)
      afrag[ni] = *(const bf16x8*)&Bs[(ni * 16 + lr) * AP + kl];
#pragma unroll
    for (int ni = 0; ni < 8; ni++)
#pragma unroll
      for (int mi = 0; mi < 2; mi++)
        acc[ni][mi] = __builtin_amdgcn_mfma_f32_16x16x32_bf16(afrag[ni], bfrag[mi], acc[ni][mi], 0, 0, 0);
  }
  __syncthreads();

#pragma unroll
  for (int mi = 0; mi < 2; mi++) {
    int r = rbase + mi * 16 + lr;
    int gr = row0 + r;
    float nv = (gr < N) ? nrm[gr] : 0.f;
#pragma unroll
    for (int ni = 0; ni < 8; ni++) {
      int c0 = ni * 16 + (lane >> 4) * 4;
      float4 bb = *(const float4*)&b2[c0];
      ushort4 u;
      u.x = f2bf(fmaxf(acc[ni][mi][0] * nv + bb.x, 0.f));
      u.y = f2bf(fmaxf(acc[ni][mi][1] * nv + bb.y, 0.f));
      u.z = f2bf(fmaxf(acc[ni][mi][2] * nv + bb.z, 0.f));
      u.w = f2bf(fmaxf(acc[ni][mi][3] * nv + bb.w, 0.f));
      *(ushort4*)&h2s[r * H2P + c0] = u;
    }
  }
  f32x4 acc3[2];
  acc3[0] = (f32x4)0.f;
  acc3[1] = (f32x4)0.f;
#pragma unroll
  for (int ks = 0; ks < 4; ks++) {
    bf16x8 a3 = *(const bf16x8*)&w3b[(size_t)lr * 128 + ks * 32 + kl];
#pragma unroll
    for (int mi = 0; mi < 2; mi++) {
      bf16x8 b3f = *(const bf16x8*)&h2s[(rbase + mi * 16 + lr) * H2P + ks * 32 + kl];
      acc3[mi] = __builtin_amdgcn_mfma_f32_16x16x32_bf16(a3, b3f, acc3[mi], 0, 0, 0);
    }
  }
#pragma unroll
  for (int mi = 0; mi < 2; mi++) {
    int gr = row0 + rbase + mi * 16 + lr;
    if (gr < N) {
      int o0 = (lane >> 4) * 4;
      float4 bb = *(const float4*)&b3[o0];
      float4 v;
      v.x = acc3[mi][0] + bb.x;
      v.y = acc3[mi][1] + bb.y;
      v.z = acc3[mi][2] + bb.z;
      v.w = acc3[mi][3] + bb.w;
      *(float4*)&out[(size_t)gr * 16 + o0] = v;
      *(float4*)&out[(size_t)(N + gr) * 16 + o0] = v;
    }
  }
}

// ---------------- launch ----------------
extern "C" void kernel_launch(void* const* d_in, const int* in_sizes, int n_in,
                              void* d_out, int out_size, void* d_ws, size_t ws_size,
                              hipStream_t stream) {
  const int N = in_sizes[0];
  const int E = in_sizes[1] / 2;
  const int HW = (N + 3) / 4;
  const int NBUK = (N + NPB - 1) / NPB;  // <= NBUKMAX for N <= 131072
  const int nrb = (HW + 255) / 256;      // nrm-reduce blocks

  const int* e_sub = (const int*)d_in[1];
  const int* src = e_sub;
  const int* dst = e_sub + E;
  const float* feat = (const float*)d_in[3];
  const float* w1 = (const float*)d_in[4];
  const float* b1 = (const float*)d_in[5];
  const float* w2 = (const float*)d_in[6];
  const float* b2 = (const float*)d_in[7];
  const float* w3 = (const float*)d_in[8];
  const float* b3 = (const float*)d_in[9];
  float* out = (float*)d_out;

  char* p = (char*)d_ws;
  auto alloc = [&](size_t bytes) { void* r = (void*)p; p += (bytes + 255) & ~(size_t)255; return r; };
  int* row_start = (int*)alloc((size_t)(N + 1) * 4);
  int* csr = (int*)alloc((size_t)E * 4);
  int* hist = (int*)alloc((size_t)(NBUKMAX + 1) * PB * 4);
  unsigned* pairs = (unsigned*)alloc((size_t)E * 4);
  float* nrm = (float*)alloc((size_t)N * 4);
  ushort* w1P = (ushort*)alloc((size_t)128 * 256 * 2);
  ushort* w2T = (ushort*)alloc((size_t)128 * 128 * 2);
  ushort* w3b = (ushort*)alloc((size_t)16 * 128 * 2);
  ushort* Xb = (ushort*)alloc((size_t)N * 128 * 2);  // X (conv1 out), later Agg2
  ushort* Hb = (ushort*)alloc((size_t)N * 128 * 2);  // H1n (pre-scaled)
  unsigned* planes = (unsigned*)alloc((size_t)PB * HW * 4);

  // src byte-plane hist + dst bucket hist (one edge pass)
  k_hist2<<<PB, 256, 0, stream>>>(src, dst, E, planes, HW, hist);
  // nrm reduce + weight cvt (w1 fragment-packed) + bucket scan (one launch)
  k_reduce_cvt<<<nrb + 201, 256, 0, stream>>>(planes, HW, nrm, N, nrb, w1, w2, w3, w1P, w2T,
                                              w3b, hist);
  // p1 bucket-scatter (standalone — clean attribution)
  k_p1_scatter<<<PB, 256, 0, stream>>>(src, dst, E, hist, pairs);
  // conv1 GEMM (direct-fragment, 2 row-groups/wave)
  k_gemm1<<<(N + 127) / 128, 256, 0, stream>>>(feat, w1P, nrm, Xb, N);
  // CSR finalize (row_start + coalesced csr)
  k_p2_place<<<NBUK, 256, 0, stream>>>(pairs, hist, csr, row_start, N, E);
  // conv1 aggregate (+epilogue, pre-scaled)
  k_agg_bf<<<(N + 3) / 4, 256, 0, stream>>>(Xb, row_start, csr, nrm, b1, Hb, N, 1);
  // conv2 aggregate (raw)
  k_agg_bf<<<(N + 3) / 4, 256, 0, stream>>>(Hb, row_start, csr, nrm, b1, Xb, N, 0);
  // conv2 GEMM + epilogue + final linear
  k_gemm23_mfma<<<(N + 127) / 128, 256, 0, stream>>>(Xb, nrm, w2T, b2, w3b, b3, out, N);
}

// Round 16
// 283.297 us; speedup vs baseline: 1.1087x; 1.1087x over previous
//
#include <hip/hip_runtime.h>

#define AP 40      // padded LDS K-stride (bf16): 80B rows -> 2-way bank aliasing (free)
#define H2P 136    // h2 LDS row stride (bf16): 272B -> 2-way
#define PB 120     // hist/bucket-sort pass blocks
#define NPB 256    // nodes per bucket (d >> 8)
#define NBUKMAX 512
#define CAPE 8192  // LDS stage capacity (edges per bucket)

typedef short bf16x8 __attribute__((ext_vector_type(8)));
typedef float f32x4 __attribute__((ext_vector_type(4)));

static __device__ __forceinline__ ushort f2bf(float f) {
  unsigned u = __float_as_uint(f);
  unsigned r = (u + 0x7fffu + ((u >> 16) & 1u)) >> 16;  // RNE
  return (ushort)r;
}
static __device__ __forceinline__ float bflo(unsigned u) { return __uint_as_float(u << 16); }
static __device__ __forceinline__ float bfhi(unsigned u) { return __uint_as_float(u & 0xffff0000u); }
static __device__ __forceinline__ unsigned packbf(float lo, float hi) {
  return (unsigned)f2bf(lo) | ((unsigned)f2bf(hi) << 16);
}

// ---- merged: src-degree byte-plane histogram + dst bucket histogram (one edge read) ----
__global__ __launch_bounds__(256) void k_hist2(const int* __restrict__ src,
                                               const int* __restrict__ dst, int E,
                                               unsigned* __restrict__ planes, int HW,
                                               int* __restrict__ hist) {
  __shared__ unsigned lds[25600];  // 100KB byte counters (up to 102400 nodes)
  __shared__ int cnt[NBUKMAX];
  const int per = (E + PB - 1) / PB;
  const int s0 = blockIdx.x * per;
  const int s1 = min(E, s0 + per);
  for (int i = threadIdx.x; i < HW; i += 256) lds[i] = 0u;
  for (int i = threadIdx.x; i < NBUKMAX; i += 256) cnt[i] = 0;
  __syncthreads();
  for (int j = s0 + threadIdx.x; j < s1; j += 256) {
    int k = src[j];
    atomicAdd(&lds[k >> 2], 1u << ((k & 3) * 8));
    atomicAdd(&cnt[dst[j] >> 8], 1);
  }
  __syncthreads();
  unsigned* out = planes + (size_t)blockIdx.x * HW;
  for (int i = threadIdx.x; i < HW; i += 256) out[i] = lds[i];
  for (int i = threadIdx.x; i < NBUKMAX; i += 256) hist[i * PB + blockIdx.x] = cnt[i];
}

// ---- merged: plane-reduce -> nrm | weight cvt (w1 in fragment order) | bucket scan ----
__global__ void k_reduce_cvt(const unsigned* __restrict__ planes, int HW,
                             float* __restrict__ nrm, int N, int nrb,
                             const float* __restrict__ w1, const float* __restrict__ w2,
                             const float* __restrict__ w3, ushort* __restrict__ w1P,
                             ushort* __restrict__ w2T, ushort* __restrict__ w3b,
                             int* __restrict__ hist) {
  __shared__ int s[256];
  if ((int)blockIdx.x < nrb) {
    int w = blockIdx.x * 256 + threadIdx.x;
    if (w >= HW) return;
    const unsigned* base = planes + w;
    unsigned c0 = 0, c1 = 0, c2 = 0, c3 = 0;
    for (int b = 0; b < PB; b++) {
      unsigned u = base[(size_t)b * HW];
      c0 += u & 255u; c1 += (u >> 8) & 255u; c2 += (u >> 16) & 255u; c3 += u >> 24;
    }
    int n0 = w * 4;
    unsigned c[4] = {c0, c1, c2, c3};
#pragma unroll
    for (int j = 0; j < 4; j++)
      if (n0 + j < N) {
        float d = (float)c[j];
        if (d < 1.f) d = 1.f;
        nrm[n0 + j] = 1.f / sqrtf(d);
      }
  } else if ((int)blockIdx.x < nrb + 200) {
    int i = (blockIdx.x - nrb) * 256 + threadIdx.x;
    if (i < 32768) {
      // w1P: MFMA-A-fragment order. frag=(k0s*8+ni), elem=(lane,e)
      int frag = i >> 9, within = i & 511;
      int lane = within >> 3, e = within & 7;
      int k0s = frag >> 3, ni = frag & 7;
      int row = ni * 16 + (lane & 15);
      int col = k0s * 32 + (lane >> 4) * 8 + e;
      w1P[i] = f2bf(w1[col * 128 + row]);
    } else if (i < 49152) {     // w2T [128 c][128 k] <- w2 [128][128]
      int j = i - 32768;
      int c = j >> 7, k = j & 127;
      w2T[j] = f2bf(w2[k * 128 + c]);
    } else if (i < 51200) {     // w3b flat [16][128]
      int j = i - 49152;
      w3b[j] = f2bf(w3[j]);
    }
  } else {
    // exclusive scan of bucket totals; rewrite hist rows as running base offsets
    int t = threadIdx.x;
    int b0 = t * 2, b1 = t * 2 + 1;
    int tot0 = 0, tot1 = 0;
    for (int blk = 0; blk < PB; blk++) tot0 += hist[b0 * PB + blk];
    for (int blk = 0; blk < PB; blk++) tot1 += hist[b1 * PB + blk];
    int pair = tot0 + tot1;
    s[t] = pair;
    __syncthreads();
    for (int o = 1; o < 256; o <<= 1) {
      int x = (t >= o) ? s[t - o] : 0;
      __syncthreads();
      s[t] += x;
      __syncthreads();
    }
    int base = s[t] - pair;
    for (int blk = 0; blk < PB; blk++) { int v = hist[b0 * PB + blk]; hist[b0 * PB + blk] = base; base += v; }
    for (int blk = 0; blk < PB; blk++) { int v = hist[b1 * PB + blk]; hist[b1 * PB + blk] = base; base += v; }
  }
}

// ---- merged: p1 bucket-scatter (blocks [0,PB)) + GEMM1 64-row tiles (blocks [PB, ...)) ----
// gemm1: Xb[r,:] = bf16(nrm[r]*(feat[r,:] @ w1)); feat staged via LDS with register
// prefetch (issue-early/write-late); w1 A-fragments from w1P (coalesced, L2-resident).
// p1 rides along in the same launch: its 120 blocks run concurrently with gemm1's
// blocks, so the scatter's ~10-25us hides entirely under the GEMM (round-15 A/B:
// splitting them costs +26us).
__global__ __launch_bounds__(256) void k_p1_gemm1(const int* __restrict__ src,
                                                  const int* __restrict__ dst, int E,
                                                  const int* __restrict__ hist,
                                                  unsigned* __restrict__ pairs,
                                                  const float* __restrict__ feat,
                                                  const ushort* __restrict__ w1P,
                                                  const float* __restrict__ nrm,
                                                  ushort* __restrict__ Xb, int N) {
  __shared__ int cur[NBUKMAX];
  __shared__ ushort As[64 * AP];
  if ((int)blockIdx.x < PB) {
    for (int i = threadIdx.x; i < NBUKMAX; i += 256) cur[i] = hist[i * PB + blockIdx.x];
    __syncthreads();
    const int per = (E + PB - 1) / PB;
    const int s0 = blockIdx.x * per;
    const int s1 = min(E, s0 + per);
    for (int j = s0 + threadIdx.x; j < s1; j += 256) {
      int d = dst[j];
      int pos = atomicAdd(&cur[d >> 8], 1);
      pairs[pos] = ((unsigned)src[j] << 8) | (unsigned)(d & 255);
    }
    return;
  }
  const int tid = threadIdx.x;
  const int row0 = (blockIdx.x - PB) * 64;
  const int wv = tid >> 6, lane = tid & 63;
  const int rbase = wv * 16;
  const int lr = lane & 15;

  // staging geometry: thread stages row sr, cols sk..sk+8 (2 float4s)
  const int sr = tid >> 2;          // 0..63
  const int sk = (tid & 3) * 8;     // 0,8,16,24
  const int sgr = row0 + sr;
  const float* fbase = feat + (size_t)sgr * 256 + sk;
  const bool sval = (sgr < N);

  f32x4 acc[8];
#pragma unroll
  for (int ni = 0; ni < 8; ni++) acc[ni] = (f32x4)0.f;

  float4 r0 = make_float4(0.f, 0.f, 0.f, 0.f), r1 = r0;
  if (sval) { r0 = *(const float4*)fbase; r1 = *(const float4*)(fbase + 4); }

  for (int ks = 0; ks < 8; ks++) {
    // write staged regs to LDS (vmcnt drain happens here, after prior MFMAs)
    ushort4 u0, u1;
    u0.x = f2bf(r0.x); u0.y = f2bf(r0.y); u0.z = f2bf(r0.z); u0.w = f2bf(r0.w);
    u1.x = f2bf(r1.x); u1.y = f2bf(r1.y); u1.z = f2bf(r1.z); u1.w = f2bf(r1.w);
    *(ushort4*)&As[sr * AP + sk] = u0;
    *(ushort4*)&As[sr * AP + sk + 4] = u1;
    __syncthreads();
    // issue next K-step's loads early — latency hides under MFMA below
    if (ks < 7 && sval) {
      const float* fn = fbase + (ks + 1) * 32;
      r0 = *(const float4*)fn;
      r1 = *(const float4*)(fn + 4);
    }
    bf16x8 bfrag = *(const bf16x8*)&As[(rbase + lr) * AP + (lane >> 4) * 8];
    const ushort* wbase = w1P + (size_t)ks * 8 * 512 + lane * 8;
    bf16x8 afrag[8];
#pragma unroll
    for (int ni = 0; ni < 8; ni++)  // coalesced 1KB wave-reads from L2
      afrag[ni] = *(const bf16x8*)&wbase[ni * 512];
#pragma unroll
    for (int ni = 0; ni < 8; ni++)
      acc[ni] = __builtin_amdgcn_mfma_f32_16x16x32_bf16(afrag[ni], bfrag, acc[ni], 0, 0, 0);
    __syncthreads();
  }
  int gr = row0 + rbase + lr;
  if (gr < N) {
    float nv = nrm[gr];
#pragma unroll
    for (int ni = 0; ni < 8; ni++) {
      int c0 = ni * 16 + (lane >> 4) * 4;
      ushort4 u;
      u.x = f2bf(acc[ni][0] * nv);
      u.y = f2bf(acc[ni][1] * nv);
      u.z = f2bf(acc[ni][2] * nv);
      u.w = f2bf(acc[ni][3] * nv);
      *(ushort4*)&Xb[(size_t)gr * 128 + c0] = u;
    }
  }
}

// ---- p2: per-bucket CSR segment (count -> scan -> row_start + coalesced placement) ----
__global__ __launch_bounds__(256) void k_p2_place(const unsigned* __restrict__ pairs,
                                                  const int* __restrict__ hist,
                                                  int* __restrict__ csr,
                                                  int* __restrict__ row_start,
                                                  int N, int E) {
  __shared__ int stage[CAPE];
  __shared__ int cnt[NPB];
  __shared__ int scn[NPB];
  const int b = blockIdx.x;
  const int t = threadIdx.x;
  const int n0 = b << 8;
  const int n1 = min(N, n0 + NPB);
  const int nn = n1 - n0;
  const int e0 = hist[b * PB];
  const int e1 = hist[(b + 1) * PB];
  for (int i = t; i < nn; i += 256) cnt[i] = 0;
  __syncthreads();
  for (int j = e0 + t; j < e1; j += 256) atomicAdd(&cnt[pairs[j] & 255u], 1);
  __syncthreads();
  int v = (t < nn) ? cnt[t] : 0;
  scn[t] = v;
  __syncthreads();
  for (int o = 1; o < NPB; o <<= 1) {
    int x = (t >= o) ? scn[t - o] : 0;
    __syncthreads();
    scn[t] += x;
    __syncthreads();
  }
  int excl = scn[t] - v;
  if (t < nn) row_start[n0 + t] = e0 + excl;
  if (t == NPB - 1 && n1 == N) row_start[N] = e0 + scn[t];
  __syncthreads();
  if (t < nn) cnt[t] = excl;
  __syncthreads();
  const int seg = e1 - e0;
  if (seg <= CAPE) {
    for (int j = e0 + t; j < e1; j += 256) {
      unsigned pr = pairs[j];
      int rpos = atomicAdd(&cnt[pr & 255u], 1);
      stage[rpos] = (int)(pr >> 8);
    }
    __syncthreads();
    for (int j = t; j < seg; j += 256) csr[e0 + j] = stage[j];
  } else {
    for (int j = e0 + t; j < e1; j += 256) {
      unsigned pr = pairs[j];
      int rpos = atomicAdd(&cnt[pr & 255u], 1);
      csr[e0 + rpos] = (int)(pr >> 8);
    }
  }
}

// ---------------- Edge aggregation (bf16 in, fp32 accum, bf16 out) ----------------
// fused=1: Out = bf16(relu(sum*nrm+bias)*nrm) ; fused=0: Out = bf16(sum)
__global__ __launch_bounds__(256) void k_agg_bf(const ushort* __restrict__ Xin,
                                                const int* __restrict__ rs,
                                                const int* __restrict__ csr,
                                                const float* __restrict__ nrm,
                                                const float* __restrict__ bias,
                                                ushort* __restrict__ Out, int N, int fused) {
  const int wv = threadIdx.x >> 6, lane = threadIdx.x & 63;
  const int d = blockIdx.x * 4 + wv;
  if (d >= N) return;
  const unsigned* X = (const unsigned*)Xin;
  int s0 = rs[d], s1 = rs[d + 1];
  float a0 = 0.f, a1 = 0.f;
  int j = s0;
  for (; j + 4 <= s1; j += 4) {
    int i0 = csr[j], i1 = csr[j + 1], i2 = csr[j + 2], i3 = csr[j + 3];
    unsigned u0 = X[(size_t)i0 * 64 + lane];
    unsigned u1 = X[(size_t)i1 * 64 + lane];
    unsigned u2 = X[(size_t)i2 * 64 + lane];
    unsigned u3 = X[(size_t)i3 * 64 + lane];
    a0 += (bflo(u0) + bflo(u1)) + (bflo(u2) + bflo(u3));
    a1 += (bfhi(u0) + bfhi(u1)) + (bfhi(u2) + bfhi(u3));
  }
  for (; j < s1; j++) {
    unsigned u = X[(size_t)csr[j] * 64 + lane];
    a0 += bflo(u);
    a1 += bfhi(u);
  }
  unsigned o;
  if (fused) {
    float nv = nrm[d];
    float2 b = *(const float2*)&bias[lane * 2];
    float h0 = fmaxf(a0 * nv + b.x, 0.f) * nv;
    float h1 = fmaxf(a1 * nv + b.y, 0.f) * nv;
    o = packbf(h0, h1);
  } else {
    o = packbf(a0, a1);
  }
  ((unsigned*)Out)[(size_t)d * 64 + lane] = o;
}

// ---------------- GEMM2+3 (MFMA): h2=relu((Agg2@w2)*nrm+b2); out=h2@w3^T+b3 (x2) ----------------
__global__ __launch_bounds__(256) void k_gemm23_mfma(const ushort* __restrict__ Agg2,
                                                     const float* __restrict__ nrm,
                                                     const ushort* __restrict__ w2T,
                                                     const float* __restrict__ b2,
                                                     const ushort* __restrict__ w3b,
                                                     const float* __restrict__ b3,
                                                     float* __restrict__ out, int N) {
  __shared__ __align__(16) char lds_raw[128 * H2P * 2];
  ushort* As = (ushort*)lds_raw;
  ushort* Bs = As + 128 * AP;
  ushort* h2s = (ushort*)lds_raw;

  const int tid = threadIdx.x;
  const int row0 = blockIdx.x * 128;
  const int wv = tid >> 6, lane = tid & 63;
  const int rbase = wv * 32;
  const int lr = lane & 15;
  const int kl = (lane >> 4) * 8;

  f32x4 acc[8][2];
#pragma unroll
  for (int ni = 0; ni < 8; ni++)
#pragma unroll
    for (int mi = 0; mi < 2; mi++) acc[ni][mi] = (f32x4)0.f;

  for (int k0 = 0; k0 < 128; k0 += 32) {
    __syncthreads();
#pragma unroll
    for (int j = 0; j < 4; j++) {
      int e = (tid + j * 256) * 4;
      int r = e >> 5, k = e & 31;
      int gr = row0 + r;
      ushort4 v = make_ushort4(0, 0, 0, 0);
      if (gr < N) v = *(const ushort4*)&Agg2[(size_t)gr * 128 + k0 + k];
      *(ushort4*)&As[r * AP + k] = v;
    }
#pragma unroll
    for (int j = 0; j < 4; j++) {
      int e = (tid + j * 256) * 4;
      int c = e >> 5, k = e & 31;
      ushort4 v = *(const ushort4*)&w2T[(size_t)c * 128 + k0 + k];
      *(ushort4*)&Bs[c * AP + k] = v;
    }
    __syncthreads();
    bf16x8 bfrag[2], afrag[8];
#pragma unroll
    for (int mi = 0; mi < 2; mi++)
      bfrag[mi] = *(const bf16x8*)&As[(rbase + mi * 16 + lr) * AP + kl];
#pragma unroll
    for (int ni = 0; ni < 8; ni++)
      afrag[ni] = *(const bf16x8*)&Bs[(ni * 16 + lr) * AP + kl];
#pragma unroll
    for (int ni = 0; ni < 8; ni++)
#pragma unroll
      for (int mi = 0; mi < 2; mi++)
        acc[ni][mi] = __builtin_amdgcn_mfma_f32_16x16x32_bf16(afrag[ni], bfrag[mi], acc[ni][mi], 0, 0, 0);
  }
  __syncthreads();

#pragma unroll
  for (int mi = 0; mi < 2; mi++) {
    int r = rbase + mi * 16 + lr;
    int gr = row0 + r;
    float nv = (gr < N) ? nrm[gr] : 0.f;
#pragma unroll
    for (int ni = 0; ni < 8; ni++) {
      int c0 = ni * 16 + (lane >> 4) * 4;
      float4 bb = *(const float4*)&b2[c0];
      ushort4 u;
      u.x = f2bf(fmaxf(acc[ni][mi][0] * nv + bb.x, 0.f));
      u.y = f2bf(fmaxf(acc[ni][mi][1] * nv + bb.y, 0.f));
      u.z = f2bf(fmaxf(acc[ni][mi][2] * nv + bb.z, 0.f));
      u.w = f2bf(fmaxf(acc[ni][mi][3] * nv + bb.w, 0.f));
      *(ushort4*)&h2s[r * H2P + c0] = u;
    }
  }
  f32x4 acc3[2];
  acc3[0] = (f32x4)0.f;
  acc3[1] = (f32x4)0.f;
#pragma unroll
  for (int ks = 0; ks < 4; ks++) {
    bf16x8 a3 = *(const bf16x8*)&w3b[(size_t)lr * 128 + ks * 32 + kl];
#pragma unroll
    for (int mi = 0; mi < 2; mi++) {
      bf16x8 b3f = *(const bf16x8*)&h2s[(rbase + mi * 16 + lr) * H2P + ks * 32 + kl];
      acc3[mi] = __builtin_amdgcn_mfma_f32_16x16x32_bf16(a3, b3f, acc3[mi], 0, 0, 0);
    }
  }
#pragma unroll
  for (int mi = 0; mi < 2; mi++) {
    int gr = row0 + rbase + mi * 16 + lr;
    if (gr < N) {
      int o0 = (lane >> 4) * 4;
      float4 bb = *(const float4*)&b3[o0];
      float4 v;
      v.x = acc3[mi][0] + bb.x;
      v.y = acc3[mi][1] + bb.y;
      v.z = acc3[mi][2] + bb.z;
      v.w = acc3[mi][3] + bb.w;
      *(float4*)&out[(size_t)gr * 16 + o0] = v;
      *(float4*)&out[(size_t)(N + gr) * 16 + o0] = v;
    }
  }
}

// ---------------- launch ----------------
extern "C" void kernel_launch(void* const* d_in, const int* in_sizes, int n_in,
                              void* d_out, int out_size, void* d_ws, size_t ws_size,
                              hipStream_t stream) {
  const int N = in_sizes[0];
  const int E = in_sizes[1] / 2;
  const int HW = (N + 3) / 4;
  const int NBUK = (N + NPB - 1) / NPB;  // <= NBUKMAX for N <= 131072
  const int nrb = (HW + 255) / 256;      // nrm-reduce blocks

  const int* e_sub = (const int*)d_in[1];
  const int* src = e_sub;
  const int* dst = e_sub + E;
  const float* feat = (const float*)d_in[3];
  const float* w1 = (const float*)d_in[4];
  const float* b1 = (const float*)d_in[5];
  const float* w2 = (const float*)d_in[6];
  const float* b2 = (const float*)d_in[7];
  const float* w3 = (const float*)d_in[8];
  const float* b3 = (const float*)d_in[9];
  float* out = (float*)d_out;

  char* p = (char*)d_ws;
  auto alloc = [&](size_t bytes) { void* r = (void*)p; p += (bytes + 255) & ~(size_t)255; return r; };
  int* row_start = (int*)alloc((size_t)(N + 1) * 4);
  int* csr = (int*)alloc((size_t)E * 4);
  int* hist = (int*)alloc((size_t)(NBUKMAX + 1) * PB * 4);
  unsigned* pairs = (unsigned*)alloc((size_t)E * 4);
  float* nrm = (float*)alloc((size_t)N * 4);
  ushort* w1P = (ushort*)alloc((size_t)128 * 256 * 2);
  ushort* w2T = (ushort*)alloc((size_t)128 * 128 * 2);
  ushort* w3b = (ushort*)alloc((size_t)16 * 128 * 2);
  ushort* Xb = (ushort*)alloc((size_t)N * 128 * 2);  // X (conv1 out), later Agg2
  ushort* Hb = (ushort*)alloc((size_t)N * 128 * 2);  // H1n (pre-scaled)
  unsigned* planes = (unsigned*)alloc((size_t)PB * HW * 4);

  // src byte-plane hist + dst bucket hist (one edge pass)
  k_hist2<<<PB, 256, 0, stream>>>(src, dst, E, planes, HW, hist);
  // nrm reduce + weight cvt (w1 fragment-packed) + bucket scan (one launch)
  k_reduce_cvt<<<nrb + 201, 256, 0, stream>>>(planes, HW, nrm, N, nrb, w1, w2, w3, w1P, w2T,
                                              w3b, hist);
  // p1 bucket-scatter hidden under conv1 GEMM (64-row tiles, reg-prefetch) — round-12 best
  k_p1_gemm1<<<PB + (N + 63) / 64, 256, 0, stream>>>(src, dst, E, hist, pairs, feat, w1P,
                                                     nrm, Xb, N);
  // CSR finalize (row_start + coalesced csr)
  k_p2_place<<<NBUK, 256, 0, stream>>>(pairs, hist, csr, row_start, N, E);
  // conv1 aggregate (+epilogue, pre-scaled)
  k_agg_bf<<<(N + 3) / 4, 256, 0, stream>>>(Xb, row_start, csr, nrm, b1, Hb, N, 1);
  // conv2 aggregate (raw)
  k_agg_bf<<<(N + 3) / 4, 256, 0, stream>>>(Hb, row_start, csr, nrm, b1, Xb, N, 0);
  // conv2 GEMM + epilogue + final linear
  k_gemm23_mfma<<<(N + 127) / 128, 256, 0, stream>>>(Xb, nrm, w2T, b2, w3b, b3, out, N);
}